// Round 10
// baseline (4107.060 us; speedup 1.0000x reference)
//
#include <hip/hip_runtime.h>
#include <stdint.h>

// Problem constants (from reference)
#define B_N 2048
#define T_N 100
#define H_N 256
#define L_N 128
#define NV_N 5
#define COLS 512               // columns of all_hidden_states

#define KCS 384                // H + L rows of Wcs
#define RB 8                   // batch rows per block

// ---- MFMA geometry (gru_mfma) ----
#define KT_N 9                 // 9 k-tiles x 32 = K=288: h at k=0..255, x at 256..260, pad
#define PZ_STR 260             // Pz/Pr row stride (floats): float4-aligned, spread banks
#define HB_STR 296             // hbf/gbf row stride (ushorts): 592B rows, 16B-aligned

// legacy VALU kernel constants (r9, kept as fp32 path + fallback)
#define NKQ 2
#define KQH 128
#define CH 16
#define NCH 8
#define HSTR 264

static constexpr int OUT_ALLH = B_N * H_N;                     // 524288
static constexpr int OUT_SEG  = OUT_ALLH + B_N * T_N * COLS;   // 105381888
static constexpr size_t WS_NEEDED = (size_t)3 * KT_N * 16 * 64 * 8 * 2;  // 442368 B

typedef __attribute__((ext_vector_type(8))) short bf16x8v;     // 8 bf16 = 4 VGPRs
typedef __attribute__((ext_vector_type(4))) float f32x4v;      // MFMA C/D

__device__ __forceinline__ float bits2f(uint32_t u) {
    union { uint32_t u; float f; } v; v.u = u; return v.f;
}
__device__ __forceinline__ uint16_t f2bf(float f) {
    union { float f; uint32_t u; } v; v.f = f;
    uint32_t r = (v.u + 0x7FFFu + ((v.u >> 16) & 1u)) >> 16;   // round-nearest-even
    return (uint16_t)r;
}

// ---------------------------------------------------------------------------
// Runtime dtype detection (verified): majority vote on fp32-exponent of W_cs.
// ---------------------------------------------------------------------------
__device__ __forceinline__ int detect_f32(const uint32_t* __restrict__ w) {
    int cnt = 0;
    #pragma unroll 8
    for (int i = 0; i < 64; ++i) {
        uint32_t e = (w[i] >> 23) & 0xFFu;
        cnt += (e >= 97u && e <= 130u) ? 1 : 0;
    }
    return cnt >= 32 ? 1 : 0;
}

// bf16 element IO (gru_mfma path; data verified bf16 on this bench)
__device__ __forceinline__ float bld1(const void* p, int idx) {
    return bits2f(((uint32_t)((const uint16_t*)p)[idx]) << 16);
}
__device__ __forceinline__ void bld4(const void* p, int idx, float f[4]) {
    uint2 u = *(const uint2*)((const uint16_t*)p + idx);
    f[0] = bits2f(u.x << 16); f[1] = bits2f(u.x & 0xFFFF0000u);
    f[2] = bits2f(u.y << 16); f[3] = bits2f(u.y & 0xFFFF0000u);
}
__device__ __forceinline__ void bst4(void* p, int idx, const float f[4]) {
    uint2 u;
    u.x = (uint32_t)f2bf(f[0]) | ((uint32_t)f2bf(f[1]) << 16);
    u.y = (uint32_t)f2bf(f[2]) | ((uint32_t)f2bf(f[3]) << 16);
    *(uint2*)((uint16_t*)p + idx) = u;
}
__device__ __forceinline__ void bst4z(void* p, int idx) {
    *(uint2*)((uint16_t*)p + idx) = make_uint2(0u, 0u);
}

// Dtype-abstracted IO for latent_fill + legacy kernels
template <bool F32> struct IO;
template <> struct IO<true> {
    using Raw2 = float2;
    static __device__ __forceinline__ Raw2 ldraw2(const void* p, int idx) {
        return *(const float2*)((const float*)p + idx);
    }
    static __device__ __forceinline__ void cvt2(const Raw2& u, float f[2]) { f[0] = u.x; f[1] = u.y; }
    static __device__ __forceinline__ void ld4(const void* p, int idx, float f[4]) {
        const float4 v = *(const float4*)((const float*)p + idx);
        f[0] = v.x; f[1] = v.y; f[2] = v.z; f[3] = v.w;
    }
    static __device__ __forceinline__ float ld1(const void* p, int idx) { return ((const float*)p)[idx]; }
    static __device__ __forceinline__ void st4(void* p, int idx, const float f[4]) {
        *(float4*)((float*)p + idx) = make_float4(f[0], f[1], f[2], f[3]);
    }
    static __device__ __forceinline__ void st4z(void* p, int idx) {
        *(float4*)((float*)p + idx) = make_float4(0.f, 0.f, 0.f, 0.f);
    }
};
template <> struct IO<false> {
    using Raw2 = uint32_t;
    static __device__ __forceinline__ Raw2 ldraw2(const void* p, int idx) {
        return *(const uint32_t*)((const uint16_t*)p + idx);
    }
    static __device__ __forceinline__ void cvt2(const Raw2& u, float f[2]) {
        f[0] = bits2f(u << 16); f[1] = bits2f(u & 0xFFFF0000u);
    }
    static __device__ __forceinline__ void ld4(const void* p, int idx, float f[4]) { bld4(p, idx, f); }
    static __device__ __forceinline__ float ld1(const void* p, int idx) { return bld1(p, idx); }
    static __device__ __forceinline__ void st4(void* p, int idx, const float f[4]) { bst4(p, idx, f); }
    static __device__ __forceinline__ void st4z(void* p, int idx) { bst4z(p, idx); }
};

__device__ __forceinline__ float sigmoid_f(float x) {
    x = fminf(fmaxf(x, -30.f), 30.f);
    return 1.f / (1.f + __expf(-x));
}
__device__ __forceinline__ float tanh_f(float x) {
    x = fminf(fmaxf(x, -15.f), 15.f);
    float e = __expf(-2.f * x);
    return (1.f - e) / (1.f + e);
}

// ---------------------------------------------------------------------------
// Kernel 1: latent fill (unchanged, verified)
// ---------------------------------------------------------------------------
template <bool F32>
__global__ __launch_bounds__(256) void latent_fill_kernel(
    const void* __restrict__ tree,
    const void* __restrict__ graph,
    const int* __restrict__ lengths,
    const void* __restrict__ Wcs_detect,
    void* __restrict__ out)
{
    __shared__ int s_is32;
    if (threadIdx.x == 0) s_is32 = detect_f32((const uint32_t*)Wcs_detect);
    __syncthreads();
    if ((s_is32 != 0) != F32) return;

    int idx = (int)(blockIdx.x * 256 + threadIdx.x);
    int c = (idx & 31) * 8;
    int bt = idx >> 5;
    int t = bt % T_N;
    int b = bt / T_N;

    int dst = OUT_ALLH + bt * COLS + H_N + c;
    if (t < lengths[b]) {
        float v[8];
        if (c < L_N) {
            IO<F32>::ld4(tree, b * L_N + c, v);
            IO<F32>::ld4(tree, b * L_N + c + 4, v + 4);
        } else {
            IO<F32>::ld4(graph, b * L_N + (c - L_N), v);
            IO<F32>::ld4(graph, b * L_N + (c - L_N) + 4, v + 4);
        }
        IO<F32>::st4(out, dst, v);
        IO<F32>::st4(out, dst + 4, v + 4);
    } else {
        IO<F32>::st4z(out, dst);
        IO<F32>::st4z(out, dst + 4);
    }
}

// ---------------------------------------------------------------------------
// Prep kernel: reorder Wz/Wr/Wh into MFMA B-fragment layout in d_ws (bf16).
//   Fragment (mat, kt, nt): lane l, elem j holds W[k][n] with
//   k = kt*32 + (l>>4)*8 + j  (K axis: 0..255 = h-weight row k+5;
//   256..260 = x-weight row k-256; >=261 zero pad),  n = nt*16 + (l&15).
//   One thread per fragment-lane -> coalesced 16B stores.
// ---------------------------------------------------------------------------
__global__ __launch_bounds__(256) void prep_kernel(
    const void* __restrict__ Wz, const void* __restrict__ Wr,
    const void* __restrict__ Wh, const void* __restrict__ Wcs_detect,
    void* __restrict__ ws)
{
    __shared__ int s_is32;
    if (threadIdx.x == 0) s_is32 = detect_f32((const uint32_t*)Wcs_detect);
    __syncthreads();
    const int is32 = s_is32;

    int g = (int)(blockIdx.x * 256 + threadIdx.x);   // 0..27647
    int lane  = g & 63;
    int rest  = g >> 6;
    int nt    = rest & 15;
    int rest2 = rest >> 4;
    int kt    = rest2 % KT_N;
    int mat   = rest2 / KT_N;
    if (mat > 2) return;

    const void* W = (mat == 0) ? Wz : (mat == 1) ? Wr : Wh;
    const int n = nt * 16 + (lane & 15);
    uint16_t u[8];
    #pragma unroll
    for (int j = 0; j < 8; ++j) {
        int k = kt * 32 + ((lane >> 4) * 8) + j;
        int srow = (k < 256) ? (k + NV_N) : ((k <= 260) ? (k - 256) : -1);
        uint16_t v = 0;
        if (srow >= 0) {
            if (is32) v = f2bf(((const float*)W)[srow * H_N + n]);
            else      v = ((const uint16_t*)W)[srow * H_N + n];
        }
        u[j] = v;
    }
    uint4 o;
    o.x = (uint32_t)u[0] | ((uint32_t)u[1] << 16);
    o.y = (uint32_t)u[2] | ((uint32_t)u[3] << 16);
    o.z = (uint32_t)u[4] | ((uint32_t)u[5] << 16);
    o.w = (uint32_t)u[6] | ((uint32_t)u[7] << 16);
    *(uint4*)((char*)ws + (size_t)g * 16) = o;
}

// ---------------------------------------------------------------------------
// Kernel 2 (MFMA, bf16 data): per block 8 batch rows, 256 thr = 4 waves.
//   mfma_f32_16x16x32_bf16, M=16 = {rows 0-7: h_hi, rows 8-15: h_lo} (bf16
//   hi/lo split of fp32 h -> one pass computes hi+lo products; gate owners
//   sum D[r]+D[8+r] => ~fp32-h precision). Each wave owns 4 n-tiles (64
//   cols), full K=288 (9 k-tiles). B-frags stream from d_ws via 3-deep
//   double-buffer (96 VGPRs); A-frags from LDS hbf/gbf (1 ds_read_b128/kt).
//   Weight traffic 802KB/block/step from L2 is the new roofline (~6us/step).
//   Gate/update/store phases + 4-barrier scheme carried from r9 (verified).
// ---------------------------------------------------------------------------
__global__ __launch_bounds__(256, 1) void gru_mfma(
    const void* __restrict__ x_seq,
    const void* __restrict__ hidden,
    const void* __restrict__ graph,
    const int* __restrict__ lengths,
    const void* __restrict__ Wcs, const void* __restrict__ bcs,
    const void* __restrict__ bz,  const void* __restrict__ br,
    const void* __restrict__ bh,
    const void* __restrict__ ws,  void* __restrict__ out)
{
    __shared__ float PzS[16 * PZ_STR];        // 16.6 KB (cs alias at init; Ph reuse)
    __shared__ float PrS[16 * PZ_STR];        // 16.6 KB
    __shared__ uint16_t hbf[16 * HB_STR];     // 9.25 KB: rows 0-7 h_hi, 8-15 h_lo; k256..260 = x
    __shared__ uint16_t gbf[16 * HB_STR];     // 9.25 KB: same for [r*h; x]
    __shared__ int s_is32;
    __shared__ int s_len[RB];

    if (threadIdx.x == 0) s_is32 = detect_f32((const uint32_t*)Wcs);
    __syncthreads();
    if (s_is32 != 0) return;   // fp32 data -> legacy kernel handles

    const int tid  = threadIdx.x;
    const int lane = tid & 63;
    const int wv   = tid >> 6;
    const int ntb  = wv * 4;           // first n-tile of this wave (4 tiles = 64 cols)
    const int ro   = tid >> 5;         // gate row owner 0..7
    const int c0g  = (tid & 31) * 8;   // gate cols

    if (tid < RB) {
        int L = lengths[blockIdx.x * RB + tid];
        s_len[tid] = min(max(L, 1), T_N);
    }
    for (int i = tid; i < 16 * HB_STR; i += 256) { hbf[i] = 0; gbf[i] = 0; }
    __syncthreads();

    const int b0  = blockIdx.x * RB;
    const int bo  = b0 + ro;
    const int len = s_len[ro];
    int maxlen = 1;
    #pragma unroll
    for (int i = 0; i < RB; ++i) maxlen = max(maxlen, s_len[i]);

    // ---- stage [hidden, graph] into PzS alias (8 rows x 388 <= 16x260) ----
    {
        float* cs = PzS;
        for (int i = tid; i < RB * KCS; i += 256) {
            int r = i / KCS, k = i - r * KCS;
            int bb = b0 + r;
            float v = (k < H_N) ? bld1(hidden, bb * H_N + k)
                                : bld1(graph,  bb * L_N + (k - H_N));
            cs[r * 388 + k] = v;
        }
    }
    __syncthreads();

    // ---- h0 = relu(cs[ro] @ Wcs + bcs) (VALU, once) ----
    float h[8];
    {
        const float* cs = PzS;
        float acc[8];
        bld4(bcs, c0g, acc); bld4(bcs, c0g + 4, acc + 4);
        for (int k = 0; k < KCS; k += 4) {
            const float4 hv = *(const float4*)&cs[ro * 388 + k];
            const float hvv[4] = {hv.x, hv.y, hv.z, hv.w};
            #pragma unroll
            for (int kk = 0; kk < 4; ++kk) {
                float w[8];
                bld4(Wcs, (k + kk) * H_N + c0g, w);
                bld4(Wcs, (k + kk) * H_N + c0g + 4, w + 4);
                #pragma unroll
                for (int j = 0; j < 8; ++j) acc[j] += hvv[kk] * w[j];
            }
        }
        #pragma unroll
        for (int j = 0; j < 8; ++j) h[j] = fmaxf(acc[j], 0.f);
    }

    float bzv[8], brv[8], bhv[8];
    bld4(bz, c0g, bzv); bld4(bz, c0g + 4, bzv + 4);
    bld4(br, c0g, brv); bld4(br, c0g + 4, brv + 4);
    bld4(bh, c0g, bhv); bld4(bh, c0g + 4, bhv + 4);

    float smax[8];
    #pragma unroll
    for (int j = 0; j < 8; ++j) smax[j] = -1e30f;

    __syncthreads();   // cs reads done (PzS free for D-partials)

#define STORE_HILO(BUF, VALS) { \
    union { bf16x8v v; uint16_t u[8]; } hi_, lo_; \
    _Pragma("unroll") \
    for (int j_ = 0; j_ < 8; ++j_) { \
        uint16_t a_ = f2bf(VALS[j_]); \
        hi_.u[j_] = a_; \
        lo_.u[j_] = f2bf(VALS[j_] - bits2f((uint32_t)a_ << 16)); \
    } \
    *(bf16x8v*)&BUF[ro * HB_STR + c0g] = hi_.v; \
    *(bf16x8v*)&BUF[(8 + ro) * HB_STR + c0g] = lo_.v; }

    // ---- h0 -> hbf; x(0) -> hbf/gbf; prefetch x(1) ----
    STORE_HILO(hbf, h)
    const int xr = tid / NV_N;
    const int xi = tid - xr * NV_N;
    float xv = 0.f;
    if (tid < RB * NV_N) {
        float x0 = bld1(x_seq, ((b0 + xr) * T_N + 0) * NV_N + xi);
        uint16_t xh = f2bf(x0);
        uint16_t xl = f2bf(x0 - bits2f((uint32_t)xh << 16));
        hbf[xr * HB_STR + 256 + xi] = xh; hbf[(8 + xr) * HB_STR + 256 + xi] = xl;
        gbf[xr * HB_STR + 256 + xi] = xh; gbf[(8 + xr) * HB_STR + 256 + xi] = xl;
        xv = bld1(x_seq, ((b0 + xr) * T_N + 1) * NV_N + xi);
    }
    __syncthreads();

    const bf16x8v* wsW = (const bf16x8v*)ws;
    float z[8];

#define LDB1(KT, S) { \
    _Pragma("unroll") \
    for (int nt_ = 0; nt_ < 4; ++nt_) { \
        Bz[S][nt_] = wsW[((0 * KT_N + (KT)) * 16 + ntb + nt_) * 64 + lane]; \
        Br[S][nt_] = wsW[((1 * KT_N + (KT)) * 16 + ntb + nt_) * 64 + lane]; \
    } }
#define MMA1(KT, S) { \
    bf16x8v a_ = *(const bf16x8v*)&hbf[(lane & 15) * HB_STR + (KT) * 32 + ((lane >> 4) * 8)]; \
    _Pragma("unroll") \
    for (int nt_ = 0; nt_ < 4; ++nt_) { \
        accz[nt_] = __builtin_amdgcn_mfma_f32_16x16x32_bf16(a_, Bz[S][nt_], accz[nt_], 0, 0, 0); \
        accr[nt_] = __builtin_amdgcn_mfma_f32_16x16x32_bf16(a_, Br[S][nt_], accr[nt_], 0, 0, 0); \
    } }
#define LDB2(KT, S) { \
    _Pragma("unroll") \
    for (int nt_ = 0; nt_ < 4; ++nt_) \
        Bh[S][nt_] = wsW[((2 * KT_N + (KT)) * 16 + ntb + nt_) * 64 + lane]; }
#define MMA2(KT, S) { \
    bf16x8v a_ = *(const bf16x8v*)&gbf[(lane & 15) * HB_STR + (KT) * 32 + ((lane >> 4) * 8)]; \
    _Pragma("unroll") \
    for (int nt_ = 0; nt_ < 4; ++nt_) \
        acch[nt_] = __builtin_amdgcn_mfma_f32_16x16x32_bf16(a_, Bh[S][nt_], acch[nt_], 0, 0, 0); }

    #pragma unroll 1
    for (int t = 0; t < maxlen; ++t) {
        // ===== pass 1: z,r partials via MFMA =====
        {
            bf16x8v Bz[3][4], Br[3][4];
            f32x4v accz[4], accr[4];
            #pragma unroll
            for (int nt_ = 0; nt_ < 4; ++nt_) {
                accz[nt_] = {0.f, 0.f, 0.f, 0.f};
                accr[nt_] = {0.f, 0.f, 0.f, 0.f};
            }
            LDB1(0, 0) LDB1(1, 1) LDB1(2, 2)
            MMA1(0, 0) LDB1(3, 0)
            MMA1(1, 1) LDB1(4, 1)
            MMA1(2, 2) LDB1(5, 2)
            MMA1(3, 0) LDB1(6, 0)
            MMA1(4, 1) LDB1(7, 1)
            MMA1(5, 2) LDB1(8, 2)
            MMA1(6, 0) MMA1(7, 1) MMA1(8, 2)
            #pragma unroll
            for (int nt_ = 0; nt_ < 4; ++nt_) {
                #pragma unroll
                for (int i_ = 0; i_ < 4; ++i_) {
                    const int m_ = (lane >> 4) * 4 + i_;
                    const int cc = (ntb + nt_) * 16 + (lane & 15);
                    PzS[m_ * PZ_STR + cc] = accz[nt_][i_];
                    PrS[m_ * PZ_STR + cc] = accr[nt_][i_];
                }
            }
        }
        __syncthreads();                           // B1

        // ===== gates z,r (owner ro, cols c0g..+7): sum hi(row ro)+lo(row 8+ro)
        {
            const float4 za = *(const float4*)&PzS[ro * PZ_STR + c0g];
            const float4 zb = *(const float4*)&PzS[ro * PZ_STR + c0g + 4];
            const float4 zc = *(const float4*)&PzS[(8 + ro) * PZ_STR + c0g];
            const float4 zd = *(const float4*)&PzS[(8 + ro) * PZ_STR + c0g + 4];
            const float4 ra = *(const float4*)&PrS[ro * PZ_STR + c0g];
            const float4 rb = *(const float4*)&PrS[ro * PZ_STR + c0g + 4];
            const float4 rc = *(const float4*)&PrS[(8 + ro) * PZ_STR + c0g];
            const float4 rd = *(const float4*)&PrS[(8 + ro) * PZ_STR + c0g + 4];
            float sz[8] = {bzv[0] + za.x + zc.x, bzv[1] + za.y + zc.y,
                           bzv[2] + za.z + zc.z, bzv[3] + za.w + zc.w,
                           bzv[4] + zb.x + zd.x, bzv[5] + zb.y + zd.y,
                           bzv[6] + zb.z + zd.z, bzv[7] + zb.w + zd.w};
            float sr[8] = {brv[0] + ra.x + rc.x, brv[1] + ra.y + rc.y,
                           brv[2] + ra.z + rc.z, brv[3] + ra.w + rc.w,
                           brv[4] + rb.x + rd.x, brv[5] + rb.y + rd.y,
                           brv[6] + rb.z + rd.z, brv[7] + rb.w + rd.w};
            float rh[8];
            #pragma unroll
            for (int j = 0; j < 8; ++j) {
                z[j]  = sigmoid_f(sz[j]);
                rh[j] = sigmoid_f(sr[j]) * h[j];
            }
            STORE_HILO(gbf, rh)
        }
        __syncthreads();                           // B2

        // ===== pass 2: candidate-h partials via MFMA =====
        {
            bf16x8v Bh[3][4];
            f32x4v acch[4];
            #pragma unroll
            for (int nt_ = 0; nt_ < 4; ++nt_) acch[nt_] = {0.f, 0.f, 0.f, 0.f};
            LDB2(0, 0) LDB2(1, 1) LDB2(2, 2)
            MMA2(0, 0) LDB2(3, 0)
            MMA2(1, 1) LDB2(4, 1)
            MMA2(2, 2) LDB2(5, 2)
            MMA2(3, 0) LDB2(6, 0)
            MMA2(4, 1) LDB2(7, 1)
            MMA2(5, 2) LDB2(8, 2)
            MMA2(6, 0) MMA2(7, 1) MMA2(8, 2)
            #pragma unroll
            for (int nt_ = 0; nt_ < 4; ++nt_) {
                #pragma unroll
                for (int i_ = 0; i_ < 4; ++i_) {
                    const int m_ = (lane >> 4) * 4 + i_;
                    PzS[m_ * PZ_STR + (ntb + nt_) * 16 + (lane & 15)] = acch[nt_][i_];
                }
            }
        }
        __syncthreads();                           // B3

        // ===== update + stores (owner) =====
        {
            const float4 ga = *(const float4*)&PzS[ro * PZ_STR + c0g];
            const float4 gb = *(const float4*)&PzS[ro * PZ_STR + c0g + 4];
            const float4 gc = *(const float4*)&PzS[(8 + ro) * PZ_STR + c0g];
            const float4 gd = *(const float4*)&PzS[(8 + ro) * PZ_STR + c0g + 4];
            float sg[8] = {bhv[0] + ga.x + gc.x, bhv[1] + ga.y + gc.y,
                           bhv[2] + ga.z + gc.z, bhv[3] + ga.w + gc.w,
                           bhv[4] + gb.x + gd.x, bhv[5] + gb.y + gd.y,
                           bhv[6] + gb.z + gd.z, bhv[7] + gb.w + gd.w};
            const bool active = (t < len);
            float hs[8];
            #pragma unroll
            for (int j = 0; j < 8; ++j) {
                float pre = tanh_f(sg[j]);
                float hn  = (1.f - z[j]) * h[j] + z[j] * pre;
                hn = active ? hn : h[j];
                h[j]  = hn;
                hs[j] = active ? hn : 0.f;
                smax[j] = active ? fmaxf(smax[j], hn) : smax[j];
            }
            const int ob = OUT_ALLH + (bo * T_N + t) * COLS + c0g;
            bst4(out, ob, hs);
            bst4(out, ob + 4, hs + 4);
            if (t == len - 1) {
                bst4(out, bo * H_N + c0g, h);
                bst4(out, bo * H_N + c0g + 4, h + 4);
            }
            STORE_HILO(hbf, h)
        }
        // stage x(t+1), prefetch x(t+2)
        if (tid < RB * NV_N) {
            uint16_t xh = f2bf(xv);
            uint16_t xl = f2bf(xv - bits2f((uint32_t)xh << 16));
            hbf[xr * HB_STR + 256 + xi] = xh; hbf[(8 + xr) * HB_STR + 256 + xi] = xl;
            gbf[xr * HB_STR + 256 + xi] = xh; gbf[(8 + xr) * HB_STR + 256 + xi] = xl;
            int tn = (t + 2 < T_N) ? (t + 2) : (T_N - 1);
            xv = bld1(x_seq, ((b0 + xr) * T_N + tn) * NV_N + xi);
        }
        __syncthreads();                           // B4
    }

#undef LDB1
#undef MMA1
#undef LDB2
#undef MMA2
#undef STORE_HILO

    for (int t = maxlen; t < T_N; ++t) {
        const int ob = OUT_ALLH + (bo * T_N + t) * COLS + c0g;
        bst4z(out, ob);
        bst4z(out, ob + 4);
    }
    bst4(out, OUT_SEG + bo * H_N + c0g, smax);
    bst4(out, OUT_SEG + bo * H_N + c0g + 4, smax + 4);
}

// ---------------------------------------------------------------------------
// Legacy VALU kernel (r9, verified passing): fp32 path + bf16 fallback when
// workspace is too small for the MFMA fragment buffer.
// ---------------------------------------------------------------------------
template <bool F32>
__global__ __launch_bounds__(256, 1) void gru_kernel(
    const void* __restrict__ x_seq,
    const void* __restrict__ hidden,
    const void* __restrict__ graph,
    const int* __restrict__ lengths,
    const void* __restrict__ Wcs, const void* __restrict__ bcs,
    const void* __restrict__ Wz,  const void* __restrict__ bz,
    const void* __restrict__ Wr,  const void* __restrict__ br,
    const void* __restrict__ Wh,  const void* __restrict__ bh,
    void* __restrict__ out)
{
    __shared__ float Pz[NKQ][RB][H_N];
    __shared__ float Pr[NKQ][RB][H_N];
    __shared__ float hstage[RB][HSTR];
    __shared__ float gstage[RB][HSTR];
    __shared__ int s_is32;
    __shared__ int s_len[RB];

    if (threadIdx.x == 0) s_is32 = detect_f32((const uint32_t*)Wcs);
    __syncthreads();
    if ((s_is32 != 0) != F32) return;

    const int tid = threadIdx.x;
    const int kq  = tid >> 7;
    const int c0  = (tid & 127) * 2;
    const int ro  = tid >> 5;
    const int c0g = (tid & 31) * 8;
    const int kh0 = kq * KQH;

    if (tid < RB) {
        int L = lengths[blockIdx.x * RB + tid];
        s_len[tid] = min(max(L, 1), T_N);
    }
    __syncthreads();

    const int b0  = blockIdx.x * RB;
    const int bo  = b0 + ro;
    const int len = s_len[ro];
    int maxlen = 1;
    #pragma unroll
    for (int i = 0; i < RB; ++i) maxlen = max(maxlen, s_len[i]);

    {
        float* cs = &Pz[0][0][0];
        for (int i = tid; i < RB * KCS; i += 256) {
            int r = i / KCS;
            int k = i - r * KCS;
            int bb = b0 + r;
            float v = (k < H_N) ? IO<F32>::ld1(hidden, bb * H_N + k)
                                : IO<F32>::ld1(graph,  bb * L_N + (k - H_N));
            cs[r * 388 + k] = v;
        }
    }
    __syncthreads();

    float h[8];
    {
        const float* cs = &Pz[0][0][0];
        float acc[8];
        IO<F32>::ld4(bcs, c0g, acc);
        IO<F32>::ld4(bcs, c0g + 4, acc + 4);
        for (int k = 0; k < KCS; k += 4) {
            const float4 hv = *reinterpret_cast<const float4*>(&cs[ro * 388 + k]);
            const float hvv[4] = {hv.x, hv.y, hv.z, hv.w};
            #pragma unroll
            for (int kk = 0; kk < 4; ++kk) {
                float w[8];
                IO<F32>::ld4(Wcs, (k + kk) * H_N + c0g, w);
                IO<F32>::ld4(Wcs, (k + kk) * H_N + c0g + 4, w + 4);
                #pragma unroll
                for (int j = 0; j < 8; ++j) acc[j] += hvv[kk] * w[j];
            }
        }
        #pragma unroll
        for (int j = 0; j < 8; ++j) h[j] = fmaxf(acc[j], 0.f);
    }

    float bzv[8], brv[8], bhv[8];
    IO<F32>::ld4(bz, c0g, bzv); IO<F32>::ld4(bz, c0g + 4, bzv + 4);
    IO<F32>::ld4(br, c0g, brv); IO<F32>::ld4(br, c0g + 4, brv + 4);
    IO<F32>::ld4(bh, c0g, bhv); IO<F32>::ld4(bh, c0g + 4, bhv + 4);

    float smax[8];
    #pragma unroll
    for (int j = 0; j < 8; ++j) smax[j] = -1e30f;

    __syncthreads();

    *reinterpret_cast<float4*>(&hstage[ro][c0g])     = make_float4(h[0], h[1], h[2], h[3]);
    *reinterpret_cast<float4*>(&hstage[ro][c0g + 4]) = make_float4(h[4], h[5], h[6], h[7]);

    const int xr = tid / NV_N;
    const int xi = tid - xr * NV_N;
    float xv = 0.f;
    if (tid < RB * NV_N) {
        float x0 = IO<F32>::ld1(x_seq, ((b0 + xr) * T_N + 0) * NV_N + xi);
        hstage[xr][H_N + xi] = x0;
        gstage[xr][H_N + xi] = x0;
        int tn = (1 < T_N) ? 1 : 0;
        xv = IO<F32>::ld1(x_seq, ((b0 + xr) * T_N + tn) * NV_N + xi);
    }
    __syncthreads();

    float z[8];
    typename IO<F32>::Raw2 zA[CH], rA[CH], zB[CH], rB[CH], hA[CH], hB[CH];
    typename IO<F32>::Raw2 xzb[NV_N], xrb[NV_N], xhb[NV_N];

#define P1_ISSUE(CHN, RZ, RR) { \
    const int kb_ = 5 + kh0 + (CHN) * CH; \
    _Pragma("unroll") \
    for (int i_ = 0; i_ < CH; ++i_) { \
        RZ[i_] = IO<F32>::ldraw2(Wz, (kb_ + i_) * H_N + c0); \
        RR[i_] = IO<F32>::ldraw2(Wr, (kb_ + i_) * H_N + c0); \
    } \
    __builtin_amdgcn_sched_barrier(0); }
#define P1_CONSUME(CHN, RZ, RR) { \
    const int kb_ = kh0 + (CHN) * CH; \
    _Pragma("unroll") \
    for (int g_ = 0; g_ < CH / 2; ++g_) { \
        float2 hr_[RB]; \
        _Pragma("unroll") \
        for (int r_ = 0; r_ < RB; ++r_) \
            hr_[r_] = *reinterpret_cast<const float2*>(&hstage[r_][kb_ + 2 * g_]); \
        _Pragma("unroll") \
        for (int u_ = 0; u_ < 2; ++u_) { \
            float wz2_[2], wr2_[2]; \
            IO<F32>::cvt2(RZ[2 * g_ + u_], wz2_); \
            IO<F32>::cvt2(RR[2 * g_ + u_], wr2_); \
            _Pragma("unroll") \
            for (int r_ = 0; r_ < RB; ++r_) { \
                const float hv_ = u_ ? hr_[r_].y : hr_[r_].x; \
                az[r_][0] += hv_ * wz2_[0]; \
                az[r_][1] += hv_ * wz2_[1]; \
                ar[r_][0] += hv_ * wr2_[0]; \
                ar[r_][1] += hv_ * wr2_[1]; \
            } } } }
#define P2_ISSUE(CHN, RH) { \
    const int kb_ = 5 + kh0 + (CHN) * CH; \
    _Pragma("unroll") \
    for (int i_ = 0; i_ < CH; ++i_) \
        RH[i_] = IO<F32>::ldraw2(Wh, (kb_ + i_) * H_N + c0); \
    __builtin_amdgcn_sched_barrier(0); }
#define P2_CONSUME(CHN, RH) { \
    const int kb_ = kh0 + (CHN) * CH; \
    _Pragma("unroll") \
    for (int g_ = 0; g_ < CH / 2; ++g_) { \
        float2 gr_[RB]; \
        _Pragma("unroll") \
        for (int r_ = 0; r_ < RB; ++r_) \
            gr_[r_] = *reinterpret_cast<const float2*>(&gstage[r_][kb_ + 2 * g_]); \
        _Pragma("unroll") \
        for (int u_ = 0; u_ < 2; ++u_) { \
            float wh2_[2]; \
            IO<F32>::cvt2(RH[2 * g_ + u_], wh2_); \
            _Pragma("unroll") \
            for (int r_ = 0; r_ < RB; ++r_) { \
                const float gv_ = u_ ? gr_[r_].y : gr_[r_].x; \
                ag[r_][0] += gv_ * wh2_[0]; \
                ag[r_][1] += gv_ * wh2_[1]; \
            } } } }
#define PX_ISSUE() if (kq == 0) { \
    _Pragma("unroll") \
    for (int i_ = 0; i_ < NV_N; ++i_) { \
        xzb[i_] = IO<F32>::ldraw2(Wz, i_ * H_N + c0); \
        xrb[i_] = IO<F32>::ldraw2(Wr, i_ * H_N + c0); \
    } }
#define PXH_ISSUE() if (kq == 0) { \
    _Pragma("unroll") \
    for (int i_ = 0; i_ < NV_N; ++i_) \
        xhb[i_] = IO<F32>::ldraw2(Wh, i_ * H_N + c0); }
#define P1X_CONSUME() if (kq == 0) { \
    _Pragma("unroll") \
    for (int i_ = 0; i_ < NV_N; ++i_) { \
        float wz2_[2], wr2_[2]; \
        IO<F32>::cvt2(xzb[i_], wz2_); \
        IO<F32>::cvt2(xrb[i_], wr2_); \
        _Pragma("unroll") \
        for (int r_ = 0; r_ < RB; ++r_) { \
            const float xv_ = hstage[r_][H_N + i_]; \
            az[r_][0] += xv_ * wz2_[0]; \
            az[r_][1] += xv_ * wz2_[1]; \
            ar[r_][0] += xv_ * wr2_[0]; \
            ar[r_][1] += xv_ * wr2_[1]; \
        } } }
#define P2X_CONSUME() if (kq == 0) { \
    _Pragma("unroll") \
    for (int i_ = 0; i_ < NV_N; ++i_) { \
        float wh2_[2]; \
        IO<F32>::cvt2(xhb[i_], wh2_); \
        _Pragma("unroll") \
        for (int r_ = 0; r_ < RB; ++r_) { \
            const float xv_ = gstage[r_][H_N + i_]; \
            ag[r_][0] += xv_ * wh2_[0]; \
            ag[r_][1] += xv_ * wh2_[1]; \
        } } }

    PX_ISSUE();
    P1_ISSUE(0, zA, rA);

    #pragma unroll 1
    for (int t = 0; t < maxlen; ++t) {
        float az[RB][2], ar[RB][2];
        #pragma unroll
        for (int r = 0; r < RB; ++r) {
            az[r][0] = 0.f; az[r][1] = 0.f;
            ar[r][0] = 0.f; ar[r][1] = 0.f;
        }
        #pragma unroll 1
        for (int ch = 0; ch < NCH; ch += 2) {
            P1_ISSUE(ch + 1, zB, rB);
            P1_CONSUME(ch, zA, rA);
            if (ch + 2 < NCH) { P1_ISSUE(ch + 2, zA, rA); }
            else              { P2_ISSUE(0, hA); PXH_ISSUE(); }
            P1_CONSUME(ch + 1, zB, rB);
        }
        P1X_CONSUME();
        #pragma unroll
        for (int r = 0; r < RB; ++r) {
            *reinterpret_cast<float2*>(&Pz[kq][r][c0]) = make_float2(az[r][0], az[r][1]);
            *reinterpret_cast<float2*>(&Pr[kq][r][c0]) = make_float2(ar[r][0], ar[r][1]);
        }
        __syncthreads();

        {
            float sz[8], sr[8];
            #pragma unroll
            for (int j = 0; j < 8; ++j) { sz[j] = bzv[j]; sr[j] = brv[j]; }
            #pragma unroll
            for (int q = 0; q < NKQ; ++q) {
                float4 a = *reinterpret_cast<const float4*>(&Pz[q][ro][c0g]);
                float4 b = *reinterpret_cast<const float4*>(&Pz[q][ro][c0g + 4]);
                sz[0] += a.x; sz[1] += a.y; sz[2] += a.z; sz[3] += a.w;
                sz[4] += b.x; sz[5] += b.y; sz[6] += b.z; sz[7] += b.w;
                a = *reinterpret_cast<const float4*>(&Pr[q][ro][c0g]);
                b = *reinterpret_cast<const float4*>(&Pr[q][ro][c0g + 4]);
                sr[0] += a.x; sr[1] += a.y; sr[2] += a.z; sr[3] += a.w;
                sr[4] += b.x; sr[5] += b.y; sr[6] += b.z; sr[7] += b.w;
            }
            float rh[8];
            #pragma unroll
            for (int j = 0; j < 8; ++j) {
                z[j] = sigmoid_f(sz[j]);
                rh[j] = sigmoid_f(sr[j]) * h[j];
            }
            *reinterpret_cast<float4*>(&gstage[ro][c0g])     = make_float4(rh[0], rh[1], rh[2], rh[3]);
            *reinterpret_cast<float4*>(&gstage[ro][c0g + 4]) = make_float4(rh[4], rh[5], rh[6], rh[7]);
        }
        __syncthreads();

        float ag[RB][2];
        #pragma unroll
        for (int r = 0; r < RB; ++r) { ag[r][0] = 0.f; ag[r][1] = 0.f; }
        #pragma unroll 1
        for (int ch = 0; ch < NCH; ch += 2) {
            P2_ISSUE(ch + 1, hB);
            P2_CONSUME(ch, hA);
            if (ch + 2 < NCH) { P2_ISSUE(ch + 2, hA); }
            else              { P1_ISSUE(0, zA, rA); PX_ISSUE(); }
            P2_CONSUME(ch + 1, hB);
        }
        P2X_CONSUME();
        #pragma unroll
        for (int r = 0; r < RB; ++r)
            *reinterpret_cast<float2*>(&Pz[kq][r][c0]) = make_float2(ag[r][0], ag[r][1]);
        __syncthreads();

        {
            float sg[8];
            #pragma unroll
            for (int j = 0; j < 8; ++j) sg[j] = bhv[j];
            #pragma unroll
            for (int q = 0; q < NKQ; ++q) {
                float4 a = *reinterpret_cast<const float4*>(&Pz[q][ro][c0g]);
                float4 b = *reinterpret_cast<const float4*>(&Pz[q][ro][c0g + 4]);
                sg[0] += a.x; sg[1] += a.y; sg[2] += a.z; sg[3] += a.w;
                sg[4] += b.x; sg[5] += b.y; sg[6] += b.z; sg[7] += b.w;
            }
            const bool active = (t < len);
            float hs[8];
            #pragma unroll
            for (int j = 0; j < 8; ++j) {
                float pre = tanh_f(sg[j]);
                float hn  = (1.f - z[j]) * h[j] + z[j] * pre;
                hn = active ? hn : h[j];
                h[j]  = hn;
                hs[j] = active ? hn : 0.f;
                smax[j] = active ? fmaxf(smax[j], hn) : smax[j];
            }
            const int ob = OUT_ALLH + (bo * T_N + t) * COLS + c0g;
            IO<F32>::st4(out, ob, hs);
            IO<F32>::st4(out, ob + 4, hs + 4);
            if (t == len - 1) {
                IO<F32>::st4(out, bo * H_N + c0g, h);
                IO<F32>::st4(out, bo * H_N + c0g + 4, h + 4);
            }
            *reinterpret_cast<float4*>(&hstage[ro][c0g])     = make_float4(h[0], h[1], h[2], h[3]);
            *reinterpret_cast<float4*>(&hstage[ro][c0g + 4]) = make_float4(h[4], h[5], h[6], h[7]);
        }
        if (tid < RB * NV_N) {
            hstage[xr][H_N + xi] = xv;
            gstage[xr][H_N + xi] = xv;
            int tn = (t + 2 < T_N) ? (t + 2) : (T_N - 1);
            xv = IO<F32>::ld1(x_seq, ((b0 + xr) * T_N + tn) * NV_N + xi);
        }
        __syncthreads();
    }

#undef P1_ISSUE
#undef P1_CONSUME
#undef P2_ISSUE
#undef P2_CONSUME
#undef PX_ISSUE
#undef PXH_ISSUE
#undef P1X_CONSUME
#undef P2X_CONSUME

    for (int t = maxlen; t < T_N; ++t) {
        const int ob = OUT_ALLH + (bo * T_N + t) * COLS + c0g;
        IO<F32>::st4z(out, ob);
        IO<F32>::st4z(out, ob + 4);
    }
    IO<F32>::st4(out, OUT_SEG + bo * H_N + c0g, smax);
    IO<F32>::st4(out, OUT_SEG + bo * H_N + c0g + 4, smax + 4);
}

extern "C" void kernel_launch(void* const* d_in, const int* in_sizes, int n_in,
                              void* d_out, int out_size, void* d_ws, size_t ws_size,
                              hipStream_t stream) {
    const void* x_seq  = d_in[0];
    const void* hidden = d_in[1];
    const void* tree   = d_in[2];
    const void* graph  = d_in[3];
    const int*  lens   = (const int*)d_in[4];
    const void* Wcs    = d_in[5];
    const void* bcs    = d_in[6];
    const void* Wz     = d_in[7];
    const void* bz     = d_in[8];
    const void* Wr     = d_in[9];
    const void* br     = d_in[10];
    const void* Wh     = d_in[11];
    const void* bh     = d_in[12];
    void* out = d_out;

    long long work = (long long)B_N * T_N * 32;
    int fill_blocks = (int)(work / 256);   // 25600

    hipLaunchKernelGGL((latent_fill_kernel<true>),  dim3(fill_blocks), dim3(256), 0, stream,
                       tree, graph, lens, Wcs, out);
    hipLaunchKernelGGL((latent_fill_kernel<false>), dim3(fill_blocks), dim3(256), 0, stream,
                       tree, graph, lens, Wcs, out);

    const bool use_mfma = (d_ws != nullptr) && (ws_size >= WS_NEEDED);
    if (use_mfma) {
        // prep: 3*9*16*64 = 27648 fragment-lanes / 256 = 108 blocks
        hipLaunchKernelGGL(prep_kernel, dim3(108), dim3(256), 0, stream,
                           Wz, Wr, Wh, Wcs, d_ws);
        // bf16 data -> MFMA kernel (self-selects); fp32 data -> legacy<true>
        hipLaunchKernelGGL(gru_mfma, dim3(B_N / RB), dim3(256), 0, stream,
                           x_seq, hidden, graph, lens,
                           Wcs, bcs, bz, br, bh, d_ws, out);
        hipLaunchKernelGGL((gru_kernel<true>), dim3(B_N / RB), dim3(256), 0, stream,
                           x_seq, hidden, graph, lens,
                           Wcs, bcs, Wz, bz, Wr, br, Wh, bh, out);
    } else {
        hipLaunchKernelGGL((gru_kernel<false>), dim3(B_N / RB), dim3(256), 0, stream,
                           x_seq, hidden, graph, lens,
                           Wcs, bcs, Wz, bz, Wr, br, Wh, bh, out);
        hipLaunchKernelGGL((gru_kernel<true>), dim3(B_N / RB), dim3(256), 0, stream,
                           x_seq, hidden, graph, lens,
                           Wcs, bcs, Wz, bz, Wr, br, Wh, bh, out);
    }
}

// Round 11
// 4093.518 us; speedup vs baseline: 1.0033x; 1.0033x over previous
//
#include <hip/hip_runtime.h>
#include <stdint.h>

// Problem constants (from reference)
#define B_N 2048
#define T_N 100
#define H_N 256
#define L_N 128
#define NV_N 5
#define COLS 512               // columns of all_hidden_states

#define KCS 384                // H + L rows of Wcs
#define RB 8                   // batch rows per block

// ---- MFMA geometry (gru_mfma) ----
#define KT_N 9                 // 9 k-tiles x 32 = K=288: h at k=0..255, x at 256..260, pad
#define PZ_STR 260             // Pz/Pr row stride (floats): float4-aligned, spread banks
#define HB_STR 296             // hbf/gbf row stride (ushorts): 592B rows, 16B-aligned

// legacy VALU kernel constants (r9, kept as fp32 path)
#define NKQ 2
#define KQH 128
#define CH 16
#define NCH 8
#define HSTR 264

static constexpr int OUT_ALLH = B_N * H_N;                     // 524288
static constexpr int OUT_SEG  = OUT_ALLH + B_N * T_N * COLS;   // 105381888

typedef __attribute__((ext_vector_type(8))) short bf16x8v;     // 8 bf16 = 4 VGPRs
typedef __attribute__((ext_vector_type(4))) float f32x4v;      // MFMA C/D

// MFMA B-fragment buffer: 3 matrices x 9 k-tiles x 16 n-tiles x 64 lanes x 8 bf16
// = 442,368 B. Module-level device global: allocated at load time (no hipMalloc,
// graph-capture safe); prep_kernel writes, gru_mfma reads (same stream -> ordered).
__device__ __align__(16) uint16_t g_frag[3 * KT_N * 16 * 64 * 8];

__device__ __forceinline__ float bits2f(uint32_t u) {
    union { uint32_t u; float f; } v; v.u = u; return v.f;
}
__device__ __forceinline__ uint16_t f2bf(float f) {
    union { float f; uint32_t u; } v; v.f = f;
    uint32_t r = (v.u + 0x7FFFu + ((v.u >> 16) & 1u)) >> 16;   // round-nearest-even
    return (uint16_t)r;
}

// ---------------------------------------------------------------------------
// Runtime dtype detection (verified): majority vote on fp32-exponent of W_cs.
// ---------------------------------------------------------------------------
__device__ __forceinline__ int detect_f32(const uint32_t* __restrict__ w) {
    int cnt = 0;
    #pragma unroll 8
    for (int i = 0; i < 64; ++i) {
        uint32_t e = (w[i] >> 23) & 0xFFu;
        cnt += (e >= 97u && e <= 130u) ? 1 : 0;
    }
    return cnt >= 32 ? 1 : 0;
}

// bf16 element IO (gru_mfma path)
__device__ __forceinline__ float bld1(const void* p, int idx) {
    return bits2f(((uint32_t)((const uint16_t*)p)[idx]) << 16);
}
__device__ __forceinline__ void bld4(const void* p, int idx, float f[4]) {
    uint2 u = *(const uint2*)((const uint16_t*)p + idx);
    f[0] = bits2f(u.x << 16); f[1] = bits2f(u.x & 0xFFFF0000u);
    f[2] = bits2f(u.y << 16); f[3] = bits2f(u.y & 0xFFFF0000u);
}
__device__ __forceinline__ void bst4(void* p, int idx, const float f[4]) {
    uint2 u;
    u.x = (uint32_t)f2bf(f[0]) | ((uint32_t)f2bf(f[1]) << 16);
    u.y = (uint32_t)f2bf(f[2]) | ((uint32_t)f2bf(f[3]) << 16);
    *(uint2*)((uint16_t*)p + idx) = u;
}
__device__ __forceinline__ void bst4z(void* p, int idx) {
    *(uint2*)((uint16_t*)p + idx) = make_uint2(0u, 0u);
}

// Dtype-abstracted IO for latent_fill + legacy fp32 kernel
template <bool F32> struct IO;
template <> struct IO<true> {
    using Raw2 = float2;
    static __device__ __forceinline__ Raw2 ldraw2(const void* p, int idx) {
        return *(const float2*)((const float*)p + idx);
    }
    static __device__ __forceinline__ void cvt2(const Raw2& u, float f[2]) { f[0] = u.x; f[1] = u.y; }
    static __device__ __forceinline__ void ld4(const void* p, int idx, float f[4]) {
        const float4 v = *(const float4*)((const float*)p + idx);
        f[0] = v.x; f[1] = v.y; f[2] = v.z; f[3] = v.w;
    }
    static __device__ __forceinline__ float ld1(const void* p, int idx) { return ((const float*)p)[idx]; }
    static __device__ __forceinline__ void st4(void* p, int idx, const float f[4]) {
        *(float4*)((float*)p + idx) = make_float4(f[0], f[1], f[2], f[3]);
    }
    static __device__ __forceinline__ void st4z(void* p, int idx) {
        *(float4*)((float*)p + idx) = make_float4(0.f, 0.f, 0.f, 0.f);
    }
};
template <> struct IO<false> {
    using Raw2 = uint32_t;
    static __device__ __forceinline__ Raw2 ldraw2(const void* p, int idx) {
        return *(const uint32_t*)((const uint16_t*)p + idx);
    }
    static __device__ __forceinline__ void cvt2(const Raw2& u, float f[2]) {
        f[0] = bits2f(u << 16); f[1] = bits2f(u & 0xFFFF0000u);
    }
    static __device__ __forceinline__ void ld4(const void* p, int idx, float f[4]) { bld4(p, idx, f); }
    static __device__ __forceinline__ float ld1(const void* p, int idx) { return bld1(p, idx); }
    static __device__ __forceinline__ void st4(void* p, int idx, const float f[4]) { bst4(p, idx, f); }
    static __device__ __forceinline__ void st4z(void* p, int idx) { bst4z(p, idx); }
};

__device__ __forceinline__ float sigmoid_f(float x) {
    x = fminf(fmaxf(x, -30.f), 30.f);
    return 1.f / (1.f + __expf(-x));
}
__device__ __forceinline__ float tanh_f(float x) {
    x = fminf(fmaxf(x, -15.f), 15.f);
    float e = __expf(-2.f * x);
    return (1.f - e) / (1.f + e);
}

// ---------------------------------------------------------------------------
// Kernel 1: latent fill (unchanged, verified)
// ---------------------------------------------------------------------------
template <bool F32>
__global__ __launch_bounds__(256) void latent_fill_kernel(
    const void* __restrict__ tree,
    const void* __restrict__ graph,
    const int* __restrict__ lengths,
    const void* __restrict__ Wcs_detect,
    void* __restrict__ out)
{
    __shared__ int s_is32;
    if (threadIdx.x == 0) s_is32 = detect_f32((const uint32_t*)Wcs_detect);
    __syncthreads();
    if ((s_is32 != 0) != F32) return;

    int idx = (int)(blockIdx.x * 256 + threadIdx.x);
    int c = (idx & 31) * 8;
    int bt = idx >> 5;
    int t = bt % T_N;
    int b = bt / T_N;

    int dst = OUT_ALLH + bt * COLS + H_N + c;
    if (t < lengths[b]) {
        float v[8];
        if (c < L_N) {
            IO<F32>::ld4(tree, b * L_N + c, v);
            IO<F32>::ld4(tree, b * L_N + c + 4, v + 4);
        } else {
            IO<F32>::ld4(graph, b * L_N + (c - L_N), v);
            IO<F32>::ld4(graph, b * L_N + (c - L_N) + 4, v + 4);
        }
        IO<F32>::st4(out, dst, v);
        IO<F32>::st4(out, dst + 4, v + 4);
    } else {
        IO<F32>::st4z(out, dst);
        IO<F32>::st4z(out, dst + 4);
    }
}

// ---------------------------------------------------------------------------
// Prep kernel: reorder Wz/Wr/Wh into MFMA B-fragment layout in g_frag (bf16).
//   Fragment (mat, kt, nt): lane l, elem j holds W[k][n] with
//   k = kt*32 + (l>>4)*8 + j  (K axis: 0..255 = h-weight row k+5;
//   256..260 = x-weight row k-256; >=261 zero pad),  n = nt*16 + (l&15).
//   One thread per fragment-lane -> coalesced 16B stores.
// ---------------------------------------------------------------------------
__global__ __launch_bounds__(256) void prep_kernel(
    const void* __restrict__ Wz, const void* __restrict__ Wr,
    const void* __restrict__ Wh, const void* __restrict__ Wcs_detect)
{
    __shared__ int s_is32;
    if (threadIdx.x == 0) s_is32 = detect_f32((const uint32_t*)Wcs_detect);
    __syncthreads();
    const int is32 = s_is32;

    int g = (int)(blockIdx.x * 256 + threadIdx.x);   // 0..27647
    int lane  = g & 63;
    int rest  = g >> 6;
    int nt    = rest & 15;
    int rest2 = rest >> 4;
    int kt    = rest2 % KT_N;
    int mat   = rest2 / KT_N;
    if (mat > 2) return;

    const void* W = (mat == 0) ? Wz : (mat == 1) ? Wr : Wh;
    const int n = nt * 16 + (lane & 15);
    uint16_t u[8];
    #pragma unroll
    for (int j = 0; j < 8; ++j) {
        int k = kt * 32 + ((lane >> 4) * 8) + j;
        int srow = (k < 256) ? (k + NV_N) : ((k <= 260) ? (k - 256) : -1);
        uint16_t v = 0;
        if (srow >= 0) {
            if (is32) v = f2bf(((const float*)W)[srow * H_N + n]);
            else      v = ((const uint16_t*)W)[srow * H_N + n];
        }
        u[j] = v;
    }
    uint4 o;
    o.x = (uint32_t)u[0] | ((uint32_t)u[1] << 16);
    o.y = (uint32_t)u[2] | ((uint32_t)u[3] << 16);
    o.z = (uint32_t)u[4] | ((uint32_t)u[5] << 16);
    o.w = (uint32_t)u[6] | ((uint32_t)u[7] << 16);
    *(uint4*)((char*)g_frag + (size_t)g * 16) = o;
}

// ---------------------------------------------------------------------------
// Kernel 2 (MFMA, bf16 data): per block 8 batch rows, 256 thr = 4 waves.
//   mfma_f32_16x16x32_bf16, M=16 = {rows 0-7: h_hi, rows 8-15: h_lo} (bf16
//   hi/lo split of fp32 h; gate owners sum D[r]+D[8+r] => ~fp32-h precision).
//   Each wave owns 4 n-tiles (64 cols), full K=288 (9 k-tiles). B-frags
//   stream from g_frag via 3-deep double-buffer (96 VGPRs); A-frags from LDS
//   hbf/gbf (1 ds_read_b128/kt). Weight traffic 442KB/block/step from L2 is
//   the expected roofline (~3.3us/step/XCD). 4-barrier scheme from r9.
// ---------------------------------------------------------------------------
__global__ __launch_bounds__(256, 1) void gru_mfma(
    const void* __restrict__ x_seq,
    const void* __restrict__ hidden,
    const void* __restrict__ graph,
    const int* __restrict__ lengths,
    const void* __restrict__ Wcs, const void* __restrict__ bcs,
    const void* __restrict__ bz,  const void* __restrict__ br,
    const void* __restrict__ bh,  void* __restrict__ out)
{
    __shared__ float PzS[16 * PZ_STR];        // 16.6 KB (cs alias at init; Ph reuse)
    __shared__ float PrS[16 * PZ_STR];        // 16.6 KB
    __shared__ uint16_t hbf[16 * HB_STR];     // 9.25 KB: rows 0-7 h_hi, 8-15 h_lo; k256..260 = x
    __shared__ uint16_t gbf[16 * HB_STR];     // 9.25 KB: same for [r*h; x]
    __shared__ int s_is32;
    __shared__ int s_len[RB];

    if (threadIdx.x == 0) s_is32 = detect_f32((const uint32_t*)Wcs);
    __syncthreads();
    if (s_is32 != 0) return;   // fp32 data -> legacy kernel handles

    const int tid  = threadIdx.x;
    const int lane = tid & 63;
    const int wv   = tid >> 6;
    const int ntb  = wv * 4;           // first n-tile of this wave (4 tiles = 64 cols)
    const int ro   = tid >> 5;         // gate row owner 0..7
    const int c0g  = (tid & 31) * 8;   // gate cols

    if (tid < RB) {
        int L = lengths[blockIdx.x * RB + tid];
        s_len[tid] = min(max(L, 1), T_N);
    }
    for (int i = tid; i < 16 * HB_STR; i += 256) { hbf[i] = 0; gbf[i] = 0; }
    __syncthreads();

    const int b0  = blockIdx.x * RB;
    const int bo  = b0 + ro;
    const int len = s_len[ro];
    int maxlen = 1;
    #pragma unroll
    for (int i = 0; i < RB; ++i) maxlen = max(maxlen, s_len[i]);

    // ---- stage [hidden, graph] into PzS alias (8 rows x 388 <= 16x260) ----
    {
        float* cs = PzS;
        for (int i = tid; i < RB * KCS; i += 256) {
            int r = i / KCS, k = i - r * KCS;
            int bb = b0 + r;
            float v = (k < H_N) ? bld1(hidden, bb * H_N + k)
                                : bld1(graph,  bb * L_N + (k - H_N));
            cs[r * 388 + k] = v;
        }
    }
    __syncthreads();

    // ---- h0 = relu(cs[ro] @ Wcs + bcs) (VALU, once) ----
    float h[8];
    {
        const float* cs = PzS;
        float acc[8];
        bld4(bcs, c0g, acc); bld4(bcs, c0g + 4, acc + 4);
        for (int k = 0; k < KCS; k += 4) {
            const float4 hv = *(const float4*)&cs[ro * 388 + k];
            const float hvv[4] = {hv.x, hv.y, hv.z, hv.w};
            #pragma unroll
            for (int kk = 0; kk < 4; ++kk) {
                float w[8];
                bld4(Wcs, (k + kk) * H_N + c0g, w);
                bld4(Wcs, (k + kk) * H_N + c0g + 4, w + 4);
                #pragma unroll
                for (int j = 0; j < 8; ++j) acc[j] += hvv[kk] * w[j];
            }
        }
        #pragma unroll
        for (int j = 0; j < 8; ++j) h[j] = fmaxf(acc[j], 0.f);
    }

    float bzv[8], brv[8], bhv[8];
    bld4(bz, c0g, bzv); bld4(bz, c0g + 4, bzv + 4);
    bld4(br, c0g, brv); bld4(br, c0g + 4, brv + 4);
    bld4(bh, c0g, bhv); bld4(bh, c0g + 4, bhv + 4);

    float smax[8];
    #pragma unroll
    for (int j = 0; j < 8; ++j) smax[j] = -1e30f;

    __syncthreads();   // cs reads done (PzS free for D-partials)

#define STORE_HILO(BUF, VALS) { \
    union { bf16x8v v; uint16_t u[8]; } hi_, lo_; \
    _Pragma("unroll") \
    for (int j_ = 0; j_ < 8; ++j_) { \
        uint16_t a_ = f2bf(VALS[j_]); \
        hi_.u[j_] = a_; \
        lo_.u[j_] = f2bf(VALS[j_] - bits2f((uint32_t)a_ << 16)); \
    } \
    *(bf16x8v*)&BUF[ro * HB_STR + c0g] = hi_.v; \
    *(bf16x8v*)&BUF[(8 + ro) * HB_STR + c0g] = lo_.v; }

    // ---- h0 -> hbf; x(0) -> hbf/gbf; prefetch x(1) ----
    STORE_HILO(hbf, h)
    const int xr = tid / NV_N;
    const int xi = tid - xr * NV_N;
    float xv = 0.f;
    if (tid < RB * NV_N) {
        float x0 = bld1(x_seq, ((b0 + xr) * T_N + 0) * NV_N + xi);
        uint16_t xh = f2bf(x0);
        uint16_t xl = f2bf(x0 - bits2f((uint32_t)xh << 16));
        hbf[xr * HB_STR + 256 + xi] = xh; hbf[(8 + xr) * HB_STR + 256 + xi] = xl;
        gbf[xr * HB_STR + 256 + xi] = xh; gbf[(8 + xr) * HB_STR + 256 + xi] = xl;
        xv = bld1(x_seq, ((b0 + xr) * T_N + 1) * NV_N + xi);
    }
    __syncthreads();

    const bf16x8v* wsW = (const bf16x8v*)g_frag;
    float z[8];

#define LDB1(KT, S) { \
    _Pragma("unroll") \
    for (int nt_ = 0; nt_ < 4; ++nt_) { \
        Bz[S][nt_] = wsW[((0 * KT_N + (KT)) * 16 + ntb + nt_) * 64 + lane]; \
        Br[S][nt_] = wsW[((1 * KT_N + (KT)) * 16 + ntb + nt_) * 64 + lane]; \
    } }
#define MMA1(KT, S) { \
    bf16x8v a_ = *(const bf16x8v*)&hbf[(lane & 15) * HB_STR + (KT) * 32 + ((lane >> 4) * 8)]; \
    _Pragma("unroll") \
    for (int nt_ = 0; nt_ < 4; ++nt_) { \
        accz[nt_] = __builtin_amdgcn_mfma_f32_16x16x32_bf16(a_, Bz[S][nt_], accz[nt_], 0, 0, 0); \
        accr[nt_] = __builtin_amdgcn_mfma_f32_16x16x32_bf16(a_, Br[S][nt_], accr[nt_], 0, 0, 0); \
    } }
#define LDB2(KT, S) { \
    _Pragma("unroll") \
    for (int nt_ = 0; nt_ < 4; ++nt_) \
        Bh[S][nt_] = wsW[((2 * KT_N + (KT)) * 16 + ntb + nt_) * 64 + lane]; }
#define MMA2(KT, S) { \
    bf16x8v a_ = *(const bf16x8v*)&gbf[(lane & 15) * HB_STR + (KT) * 32 + ((lane >> 4) * 8)]; \
    _Pragma("unroll") \
    for (int nt_ = 0; nt_ < 4; ++nt_) \
        acch[nt_] = __builtin_amdgcn_mfma_f32_16x16x32_bf16(a_, Bh[S][nt_], acch[nt_], 0, 0, 0); }

    #pragma unroll 1
    for (int t = 0; t < maxlen; ++t) {
        // ===== pass 1: z,r partials via MFMA =====
        {
            bf16x8v Bz[3][4], Br[3][4];
            f32x4v accz[4], accr[4];
            #pragma unroll
            for (int nt_ = 0; nt_ < 4; ++nt_) {
                accz[nt_] = {0.f, 0.f, 0.f, 0.f};
                accr[nt_] = {0.f, 0.f, 0.f, 0.f};
            }
            LDB1(0, 0) LDB1(1, 1) LDB1(2, 2)
            MMA1(0, 0) LDB1(3, 0)
            MMA1(1, 1) LDB1(4, 1)
            MMA1(2, 2) LDB1(5, 2)
            MMA1(3, 0) LDB1(6, 0)
            MMA1(4, 1) LDB1(7, 1)
            MMA1(5, 2) LDB1(8, 2)
            MMA1(6, 0) MMA1(7, 1) MMA1(8, 2)
            #pragma unroll
            for (int nt_ = 0; nt_ < 4; ++nt_) {
                #pragma unroll
                for (int i_ = 0; i_ < 4; ++i_) {
                    const int m_ = (lane >> 4) * 4 + i_;
                    const int cc = (ntb + nt_) * 16 + (lane & 15);
                    PzS[m_ * PZ_STR + cc] = accz[nt_][i_];
                    PrS[m_ * PZ_STR + cc] = accr[nt_][i_];
                }
            }
        }
        __syncthreads();                           // B1

        // ===== gates z,r (owner ro, cols c0g..+7): sum hi(row ro)+lo(row 8+ro)
        {
            const float4 za = *(const float4*)&PzS[ro * PZ_STR + c0g];
            const float4 zb = *(const float4*)&PzS[ro * PZ_STR + c0g + 4];
            const float4 zc = *(const float4*)&PzS[(8 + ro) * PZ_STR + c0g];
            const float4 zd = *(const float4*)&PzS[(8 + ro) * PZ_STR + c0g + 4];
            const float4 ra = *(const float4*)&PrS[ro * PZ_STR + c0g];
            const float4 rb = *(const float4*)&PrS[ro * PZ_STR + c0g + 4];
            const float4 rc = *(const float4*)&PrS[(8 + ro) * PZ_STR + c0g];
            const float4 rd = *(const float4*)&PrS[(8 + ro) * PZ_STR + c0g + 4];
            float sz[8] = {bzv[0] + za.x + zc.x, bzv[1] + za.y + zc.y,
                           bzv[2] + za.z + zc.z, bzv[3] + za.w + zc.w,
                           bzv[4] + zb.x + zd.x, bzv[5] + zb.y + zd.y,
                           bzv[6] + zb.z + zd.z, bzv[7] + zb.w + zd.w};
            float sr[8] = {brv[0] + ra.x + rc.x, brv[1] + ra.y + rc.y,
                           brv[2] + ra.z + rc.z, brv[3] + ra.w + rc.w,
                           brv[4] + rb.x + rd.x, brv[5] + rb.y + rd.y,
                           brv[6] + rb.z + rd.z, brv[7] + rb.w + rd.w};
            float rh[8];
            #pragma unroll
            for (int j = 0; j < 8; ++j) {
                z[j]  = sigmoid_f(sz[j]);
                rh[j] = sigmoid_f(sr[j]) * h[j];
            }
            STORE_HILO(gbf, rh)
        }
        __syncthreads();                           // B2

        // ===== pass 2: candidate-h partials via MFMA =====
        {
            bf16x8v Bh[3][4];
            f32x4v acch[4];
            #pragma unroll
            for (int nt_ = 0; nt_ < 4; ++nt_) acch[nt_] = {0.f, 0.f, 0.f, 0.f};
            LDB2(0, 0) LDB2(1, 1) LDB2(2, 2)
            MMA2(0, 0) LDB2(3, 0)
            MMA2(1, 1) LDB2(4, 1)
            MMA2(2, 2) LDB2(5, 2)
            MMA2(3, 0) LDB2(6, 0)
            MMA2(4, 1) LDB2(7, 1)
            MMA2(5, 2) LDB2(8, 2)
            MMA2(6, 0) MMA2(7, 1) MMA2(8, 2)
            #pragma unroll
            for (int nt_ = 0; nt_ < 4; ++nt_) {
                #pragma unroll
                for (int i_ = 0; i_ < 4; ++i_) {
                    const int m_ = (lane >> 4) * 4 + i_;
                    PzS[m_ * PZ_STR + (ntb + nt_) * 16 + (lane & 15)] = acch[nt_][i_];
                }
            }
        }
        __syncthreads();                           // B3

        // ===== update + stores (owner) =====
        {
            const float4 ga = *(const float4*)&PzS[ro * PZ_STR + c0g];
            const float4 gb = *(const float4*)&PzS[ro * PZ_STR + c0g + 4];
            const float4 gc = *(const float4*)&PzS[(8 + ro) * PZ_STR + c0g];
            const float4 gd = *(const float4*)&PzS[(8 + ro) * PZ_STR + c0g + 4];
            float sg[8] = {bhv[0] + ga.x + gc.x, bhv[1] + ga.y + gc.y,
                           bhv[2] + ga.z + gc.z, bhv[3] + ga.w + gc.w,
                           bhv[4] + gb.x + gd.x, bhv[5] + gb.y + gd.y,
                           bhv[6] + gb.z + gd.z, bhv[7] + gb.w + gd.w};
            const bool active = (t < len);
            float hs[8];
            #pragma unroll
            for (int j = 0; j < 8; ++j) {
                float pre = tanh_f(sg[j]);
                float hn  = (1.f - z[j]) * h[j] + z[j] * pre;
                hn = active ? hn : h[j];
                h[j]  = hn;
                hs[j] = active ? hn : 0.f;
                smax[j] = active ? fmaxf(smax[j], hn) : smax[j];
            }
            const int ob = OUT_ALLH + (bo * T_N + t) * COLS + c0g;
            bst4(out, ob, hs);
            bst4(out, ob + 4, hs + 4);
            if (t == len - 1) {
                bst4(out, bo * H_N + c0g, h);
                bst4(out, bo * H_N + c0g + 4, h + 4);
            }
            STORE_HILO(hbf, h)
        }
        // stage x(t+1), prefetch x(t+2)
        if (tid < RB * NV_N) {
            uint16_t xh = f2bf(xv);
            uint16_t xl = f2bf(xv - bits2f((uint32_t)xh << 16));
            hbf[xr * HB_STR + 256 + xi] = xh; hbf[(8 + xr) * HB_STR + 256 + xi] = xl;
            gbf[xr * HB_STR + 256 + xi] = xh; gbf[(8 + xr) * HB_STR + 256 + xi] = xl;
            int tn = (t + 2 < T_N) ? (t + 2) : (T_N - 1);
            xv = bld1(x_seq, ((b0 + xr) * T_N + tn) * NV_N + xi);
        }
        __syncthreads();                           // B4
    }

#undef LDB1
#undef MMA1
#undef LDB2
#undef MMA2
#undef STORE_HILO

    for (int t = maxlen; t < T_N; ++t) {
        const int ob = OUT_ALLH + (bo * T_N + t) * COLS + c0g;
        bst4z(out, ob);
        bst4z(out, ob + 4);
    }
    bst4(out, OUT_SEG + bo * H_N + c0g, smax);
    bst4(out, OUT_SEG + bo * H_N + c0g + 4, smax + 4);
}

// ---------------------------------------------------------------------------
// Legacy VALU kernel (r9, verified): fp32-data path only (<true> instantiated).
// ---------------------------------------------------------------------------
template <bool F32>
__global__ __launch_bounds__(256, 1) void gru_kernel(
    const void* __restrict__ x_seq,
    const void* __restrict__ hidden,
    const void* __restrict__ graph,
    const int* __restrict__ lengths,
    const void* __restrict__ Wcs, const void* __restrict__ bcs,
    const void* __restrict__ Wz,  const void* __restrict__ bz,
    const void* __restrict__ Wr,  const void* __restrict__ br,
    const void* __restrict__ Wh,  const void* __restrict__ bh,
    void* __restrict__ out)
{
    __shared__ float Pz[NKQ][RB][H_N];
    __shared__ float Pr[NKQ][RB][H_N];
    __shared__ float hstage[RB][HSTR];
    __shared__ float gstage[RB][HSTR];
    __shared__ int s_is32;
    __shared__ int s_len[RB];

    if (threadIdx.x == 0) s_is32 = detect_f32((const uint32_t*)Wcs);
    __syncthreads();
    if ((s_is32 != 0) != F32) return;

    const int tid = threadIdx.x;
    const int kq  = tid >> 7;
    const int c0  = (tid & 127) * 2;
    const int ro  = tid >> 5;
    const int c0g = (tid & 31) * 8;
    const int kh0 = kq * KQH;

    if (tid < RB) {
        int L = lengths[blockIdx.x * RB + tid];
        s_len[tid] = min(max(L, 1), T_N);
    }
    __syncthreads();

    const int b0  = blockIdx.x * RB;
    const int bo  = b0 + ro;
    const int len = s_len[ro];
    int maxlen = 1;
    #pragma unroll
    for (int i = 0; i < RB; ++i) maxlen = max(maxlen, s_len[i]);

    {
        float* cs = &Pz[0][0][0];
        for (int i = tid; i < RB * KCS; i += 256) {
            int r = i / KCS;
            int k = i - r * KCS;
            int bb = b0 + r;
            float v = (k < H_N) ? IO<F32>::ld1(hidden, bb * H_N + k)
                                : IO<F32>::ld1(graph,  bb * L_N + (k - H_N));
            cs[r * 388 + k] = v;
        }
    }
    __syncthreads();

    float h[8];
    {
        const float* cs = &Pz[0][0][0];
        float acc[8];
        IO<F32>::ld4(bcs, c0g, acc);
        IO<F32>::ld4(bcs, c0g + 4, acc + 4);
        for (int k = 0; k < KCS; k += 4) {
            const float4 hv = *reinterpret_cast<const float4*>(&cs[ro * 388 + k]);
            const float hvv[4] = {hv.x, hv.y, hv.z, hv.w};
            #pragma unroll
            for (int kk = 0; kk < 4; ++kk) {
                float w[8];
                IO<F32>::ld4(Wcs, (k + kk) * H_N + c0g, w);
                IO<F32>::ld4(Wcs, (k + kk) * H_N + c0g + 4, w + 4);
                #pragma unroll
                for (int j = 0; j < 8; ++j) acc[j] += hvv[kk] * w[j];
            }
        }
        #pragma unroll
        for (int j = 0; j < 8; ++j) h[j] = fmaxf(acc[j], 0.f);
    }

    float bzv[8], brv[8], bhv[8];
    IO<F32>::ld4(bz, c0g, bzv); IO<F32>::ld4(bz, c0g + 4, bzv + 4);
    IO<F32>::ld4(br, c0g, brv); IO<F32>::ld4(br, c0g + 4, brv + 4);
    IO<F32>::ld4(bh, c0g, bhv); IO<F32>::ld4(bh, c0g + 4, bhv + 4);

    float smax[8];
    #pragma unroll
    for (int j = 0; j < 8; ++j) smax[j] = -1e30f;

    __syncthreads();

    *reinterpret_cast<float4*>(&hstage[ro][c0g])     = make_float4(h[0], h[1], h[2], h[3]);
    *reinterpret_cast<float4*>(&hstage[ro][c0g + 4]) = make_float4(h[4], h[5], h[6], h[7]);

    const int xr = tid / NV_N;
    const int xi = tid - xr * NV_N;
    float xv = 0.f;
    if (tid < RB * NV_N) {
        float x0 = IO<F32>::ld1(x_seq, ((b0 + xr) * T_N + 0) * NV_N + xi);
        hstage[xr][H_N + xi] = x0;
        gstage[xr][H_N + xi] = x0;
        int tn = (1 < T_N) ? 1 : 0;
        xv = IO<F32>::ld1(x_seq, ((b0 + xr) * T_N + tn) * NV_N + xi);
    }
    __syncthreads();

    float z[8];
    typename IO<F32>::Raw2 zA[CH], rA[CH], zB[CH], rB[CH], hA[CH], hB[CH];
    typename IO<F32>::Raw2 xzb[NV_N], xrb[NV_N], xhb[NV_N];

#define P1_ISSUE(CHN, RZ, RR) { \
    const int kb_ = 5 + kh0 + (CHN) * CH; \
    _Pragma("unroll") \
    for (int i_ = 0; i_ < CH; ++i_) { \
        RZ[i_] = IO<F32>::ldraw2(Wz, (kb_ + i_) * H_N + c0); \
        RR[i_] = IO<F32>::ldraw2(Wr, (kb_ + i_) * H_N + c0); \
    } \
    __builtin_amdgcn_sched_barrier(0); }
#define P1_CONSUME(CHN, RZ, RR) { \
    const int kb_ = kh0 + (CHN) * CH; \
    _Pragma("unroll") \
    for (int g_ = 0; g_ < CH / 2; ++g_) { \
        float2 hr_[RB]; \
        _Pragma("unroll") \
        for (int r_ = 0; r_ < RB; ++r_) \
            hr_[r_] = *reinterpret_cast<const float2*>(&hstage[r_][kb_ + 2 * g_]); \
        _Pragma("unroll") \
        for (int u_ = 0; u_ < 2; ++u_) { \
            float wz2_[2], wr2_[2]; \
            IO<F32>::cvt2(RZ[2 * g_ + u_], wz2_); \
            IO<F32>::cvt2(RR[2 * g_ + u_], wr2_); \
            _Pragma("unroll") \
            for (int r_ = 0; r_ < RB; ++r_) { \
                const float hv_ = u_ ? hr_[r_].y : hr_[r_].x; \
                az[r_][0] += hv_ * wz2_[0]; \
                az[r_][1] += hv_ * wz2_[1]; \
                ar[r_][0] += hv_ * wr2_[0]; \
                ar[r_][1] += hv_ * wr2_[1]; \
            } } } }
#define P2_ISSUE(CHN, RH) { \
    const int kb_ = 5 + kh0 + (CHN) * CH; \
    _Pragma("unroll") \
    for (int i_ = 0; i_ < CH; ++i_) \
        RH[i_] = IO<F32>::ldraw2(Wh, (kb_ + i_) * H_N + c0); \
    __builtin_amdgcn_sched_barrier(0); }
#define P2_CONSUME(CHN, RH) { \
    const int kb_ = kh0 + (CHN) * CH; \
    _Pragma("unroll") \
    for (int g_ = 0; g_ < CH / 2; ++g_) { \
        float2 gr_[RB]; \
        _Pragma("unroll") \
        for (int r_ = 0; r_ < RB; ++r_) \
            gr_[r_] = *reinterpret_cast<const float2*>(&gstage[r_][kb_ + 2 * g_]); \
        _Pragma("unroll") \
        for (int u_ = 0; u_ < 2; ++u_) { \
            float wh2_[2]; \
            IO<F32>::cvt2(RH[2 * g_ + u_], wh2_); \
            _Pragma("unroll") \
            for (int r_ = 0; r_ < RB; ++r_) { \
                const float gv_ = u_ ? gr_[r_].y : gr_[r_].x; \
                ag[r_][0] += gv_ * wh2_[0]; \
                ag[r_][1] += gv_ * wh2_[1]; \
            } } } }
#define PX_ISSUE() if (kq == 0) { \
    _Pragma("unroll") \
    for (int i_ = 0; i_ < NV_N; ++i_) { \
        xzb[i_] = IO<F32>::ldraw2(Wz, i_ * H_N + c0); \
        xrb[i_] = IO<F32>::ldraw2(Wr, i_ * H_N + c0); \
    } }
#define PXH_ISSUE() if (kq == 0) { \
    _Pragma("unroll") \
    for (int i_ = 0; i_ < NV_N; ++i_) \
        xhb[i_] = IO<F32>::ldraw2(Wh, i_ * H_N + c0); }
#define P1X_CONSUME() if (kq == 0) { \
    _Pragma("unroll") \
    for (int i_ = 0; i_ < NV_N; ++i_) { \
        float wz2_[2], wr2_[2]; \
        IO<F32>::cvt2(xzb[i_], wz2_); \
        IO<F32>::cvt2(xrb[i_], wr2_); \
        _Pragma("unroll") \
        for (int r_ = 0; r_ < RB; ++r_) { \
            const float xv_ = hstage[r_][H_N + i_]; \
            az[r_][0] += xv_ * wz2_[0]; \
            az[r_][1] += xv_ * wz2_[1]; \
            ar[r_][0] += xv_ * wr2_[0]; \
            ar[r_][1] += xv_ * wr2_[1]; \
        } } }
#define P2X_CONSUME() if (kq == 0) { \
    _Pragma("unroll") \
    for (int i_ = 0; i_ < NV_N; ++i_) { \
        float wh2_[2]; \
        IO<F32>::cvt2(xhb[i_], wh2_); \
        _Pragma("unroll") \
        for (int r_ = 0; r_ < RB; ++r_) { \
            const float xv_ = gstage[r_][H_N + i_]; \
            ag[r_][0] += xv_ * wh2_[0]; \
            ag[r_][1] += xv_ * wh2_[1]; \
        } } }

    PX_ISSUE();
    P1_ISSUE(0, zA, rA);

    #pragma unroll 1
    for (int t = 0; t < maxlen; ++t) {
        float az[RB][2], ar[RB][2];
        #pragma unroll
        for (int r = 0; r < RB; ++r) {
            az[r][0] = 0.f; az[r][1] = 0.f;
            ar[r][0] = 0.f; ar[r][1] = 0.f;
        }
        #pragma unroll 1
        for (int ch = 0; ch < NCH; ch += 2) {
            P1_ISSUE(ch + 1, zB, rB);
            P1_CONSUME(ch, zA, rA);
            if (ch + 2 < NCH) { P1_ISSUE(ch + 2, zA, rA); }
            else              { P2_ISSUE(0, hA); PXH_ISSUE(); }
            P1_CONSUME(ch + 1, zB, rB);
        }
        P1X_CONSUME();
        #pragma unroll
        for (int r = 0; r < RB; ++r) {
            *reinterpret_cast<float2*>(&Pz[kq][r][c0]) = make_float2(az[r][0], az[r][1]);
            *reinterpret_cast<float2*>(&Pr[kq][r][c0]) = make_float2(ar[r][0], ar[r][1]);
        }
        __syncthreads();

        {
            float sz[8], sr[8];
            #pragma unroll
            for (int j = 0; j < 8; ++j) { sz[j] = bzv[j]; sr[j] = brv[j]; }
            #pragma unroll
            for (int q = 0; q < NKQ; ++q) {
                float4 a = *reinterpret_cast<const float4*>(&Pz[q][ro][c0g]);
                float4 b = *reinterpret_cast<const float4*>(&Pz[q][ro][c0g + 4]);
                sz[0] += a.x; sz[1] += a.y; sz[2] += a.z; sz[3] += a.w;
                sz[4] += b.x; sz[5] += b.y; sz[6] += b.z; sz[7] += b.w;
                a = *reinterpret_cast<const float4*>(&Pr[q][ro][c0g]);
                b = *reinterpret_cast<const float4*>(&Pr[q][ro][c0g + 4]);
                sr[0] += a.x; sr[1] += a.y; sr[2] += a.z; sr[3] += a.w;
                sr[4] += b.x; sr[5] += b.y; sr[6] += b.z; sr[7] += b.w;
            }
            float rh[8];
            #pragma unroll
            for (int j = 0; j < 8; ++j) {
                z[j] = sigmoid_f(sz[j]);
                rh[j] = sigmoid_f(sr[j]) * h[j];
            }
            *reinterpret_cast<float4*>(&gstage[ro][c0g])     = make_float4(rh[0], rh[1], rh[2], rh[3]);
            *reinterpret_cast<float4*>(&gstage[ro][c0g + 4]) = make_float4(rh[4], rh[5], rh[6], rh[7]);
        }
        __syncthreads();

        float ag[RB][2];
        #pragma unroll
        for (int r = 0; r < RB; ++r) { ag[r][0] = 0.f; ag[r][1] = 0.f; }
        #pragma unroll 1
        for (int ch = 0; ch < NCH; ch += 2) {
            P2_ISSUE(ch + 1, hB);
            P2_CONSUME(ch, hA);
            if (ch + 2 < NCH) { P2_ISSUE(ch + 2, hA); }
            else              { P1_ISSUE(0, zA, rA); PX_ISSUE(); }
            P2_CONSUME(ch + 1, hB);
        }
        P2X_CONSUME();
        #pragma unroll
        for (int r = 0; r < RB; ++r)
            *reinterpret_cast<float2*>(&Pz[kq][r][c0]) = make_float2(ag[r][0], ag[r][1]);
        __syncthreads();

        {
            float sg[8];
            #pragma unroll
            for (int j = 0; j < 8; ++j) sg[j] = bhv[j];
            #pragma unroll
            for (int q = 0; q < NKQ; ++q) {
                float4 a = *reinterpret_cast<const float4*>(&Pz[q][ro][c0g]);
                float4 b = *reinterpret_cast<const float4*>(&Pz[q][ro][c0g + 4]);
                sg[0] += a.x; sg[1] += a.y; sg[2] += a.z; sg[3] += a.w;
                sg[4] += b.x; sg[5] += b.y; sg[6] += b.z; sg[7] += b.w;
            }
            const bool active = (t < len);
            float hs[8];
            #pragma unroll
            for (int j = 0; j < 8; ++j) {
                float pre = tanh_f(sg[j]);
                float hn  = (1.f - z[j]) * h[j] + z[j] * pre;
                hn = active ? hn : h[j];
                h[j]  = hn;
                hs[j] = active ? hn : 0.f;
                smax[j] = active ? fmaxf(smax[j], hn) : smax[j];
            }
            const int ob = OUT_ALLH + (bo * T_N + t) * COLS + c0g;
            IO<F32>::st4(out, ob, hs);
            IO<F32>::st4(out, ob + 4, hs + 4);
            if (t == len - 1) {
                IO<F32>::st4(out, bo * H_N + c0g, h);
                IO<F32>::st4(out, bo * H_N + c0g + 4, h + 4);
            }
            *reinterpret_cast<float4*>(&hstage[ro][c0g])     = make_float4(h[0], h[1], h[2], h[3]);
            *reinterpret_cast<float4*>(&hstage[ro][c0g + 4]) = make_float4(h[4], h[5], h[6], h[7]);
        }
        if (tid < RB * NV_N) {
            hstage[xr][H_N + xi] = xv;
            gstage[xr][H_N + xi] = xv;
            int tn = (t + 2 < T_N) ? (t + 2) : (T_N - 1);
            xv = IO<F32>::ld1(x_seq, ((b0 + xr) * T_N + tn) * NV_N + xi);
        }
        __syncthreads();
    }

#undef P1_ISSUE
#undef P1_CONSUME
#undef P2_ISSUE
#undef P2_CONSUME
#undef PX_ISSUE
#undef PXH_ISSUE
#undef P1X_CONSUME
#undef P2X_CONSUME

    for (int t = maxlen; t < T_N; ++t) {
        const int ob = OUT_ALLH + (bo * T_N + t) * COLS + c0g;
        IO<F32>::st4z(out, ob);
        IO<F32>::st4z(out, ob + 4);
    }
    IO<F32>::st4(out, OUT_SEG + bo * H_N + c0g, smax);
    IO<F32>::st4(out, OUT_SEG + bo * H_N + c0g + 4, smax + 4);
}

extern "C" void kernel_launch(void* const* d_in, const int* in_sizes, int n_in,
                              void* d_out, int out_size, void* d_ws, size_t ws_size,
                              hipStream_t stream) {
    const void* x_seq  = d_in[0];
    const void* hidden = d_in[1];
    const void* tree   = d_in[2];
    const void* graph  = d_in[3];
    const int*  lens   = (const int*)d_in[4];
    const void* Wcs    = d_in[5];
    const void* bcs    = d_in[6];
    const void* Wz     = d_in[7];
    const void* bz     = d_in[8];
    const void* Wr     = d_in[9];
    const void* br     = d_in[10];
    const void* Wh     = d_in[11];
    const void* bh     = d_in[12];
    void* out = d_out;
    (void)d_ws; (void)ws_size;

    long long work = (long long)B_N * T_N * 32;
    int fill_blocks = (int)(work / 256);   // 25600

    hipLaunchKernelGGL((latent_fill_kernel<true>),  dim3(fill_blocks), dim3(256), 0, stream,
                       tree, graph, lens, Wcs, out);
    hipLaunchKernelGGL((latent_fill_kernel<false>), dim3(fill_blocks), dim3(256), 0, stream,
                       tree, graph, lens, Wcs, out);

    // prep: 3*9*16*64 = 27648 fragment-lanes / 256 = 108 blocks -> g_frag
    hipLaunchKernelGGL(prep_kernel, dim3(108), dim3(256), 0, stream,
                       Wz, Wr, Wh, Wcs);
    // bf16 data -> MFMA kernel (self-selects); fp32 data -> legacy<true>
    hipLaunchKernelGGL(gru_mfma, dim3(B_N / RB), dim3(256), 0, stream,
                       x_seq, hidden, graph, lens,
                       Wcs, bcs, bz, br, bh, out);
    hipLaunchKernelGGL((gru_kernel<true>), dim3(B_N / RB), dim3(256), 0, stream,
                       x_seq, hidden, graph, lens,
                       Wcs, bcs, Wz, bz, Wr, br, Wh, bh, out);
}